// Round 6
// baseline (45458.746 us; speedup 1.0000x reference)
//
#include <hip/hip_runtime.h>

// Problem constants (from reference)
#define BB    2048
#define TT    100
#define CC    8
#define HD    64
#define HHD   128
#define OO    10
#define MROWS 8      // batch rows per block; grid = 256 blocks = 1 block/CU
#define NTHR  1024   // 16 waves/block = 4 waves/SIMD (R0..R5 ran 2/SIMD)

// Ledger:
// R1: 2 blocks/CU (MROWS=4): doubled per-CU weight refetch -> -35%. Reverted.
// R3: register-cached weights: FETCH 1.2e7->5e3 KB but dur FLAT -> not BW-bound.
// R4: readlane restructure: spilled (WRITE 1.5GB) -> confounded, reverted.
// R5: inline-asm ds_add_f32: SQ_LDS_BANK_CONFLICT identical to R0 => atomicAdd
//     was ALREADY native ds_add_f32; the asm "memory" clobber fenced the
//     scheduler -> -33%. Reverted to plain atomicAdd.
// Invariant: VALU-busy TIME ~3.8ms in every variant; dur 18.6-25ms = stall-
// dominated at 2 waves/SIMD. R6 (this): SAME block structure & per-CU traffic,
// but 1024-thread blocks -> 4 waves/SIMD to hide ds_read(~120cy)/L2(~200cy)
// latency. Per-thread work halves; barrier count unchanged; contention drops.

__device__ __forceinline__ float fast_tanh(float x) {
  float e = __expf(2.0f * x);
  return 1.0f - 2.0f / (e + 1.0f);
}

__global__ void zero_out_k(float* o) {
  if (threadIdx.x < 2) o[threadIdx.x] = 0.0f;
}

// Hidden layer slice: rows [rb,rb+4) staggered, k in [kb,kb+16), lane cols
// (l, l+64). Weights streamed from global (L2-hot); relu applied on read.
__device__ __forceinline__ void hidden16(const float* __restrict__ Wg,
                                         const float (*pin)[HHD],
                                         float (*pout)[HHD],
                                         int l, int kb, int rb, int stag) {
  float wx[16], wy[16];
#pragma unroll
  for (int j = 0; j < 16; ++j) {
    const float* wr = Wg + (kb + j) * HHD;
    wx[j] = wr[l];                            // 256B coalesced per wave
    wy[j] = wr[l + 64];
  }
#pragma unroll
  for (int i = 0; i < 4; ++i) {
    const int rr = rb + ((i + stag) & 3);     // stagger rows across k-slices
    const float* pr = &pin[rr][kb];
    const float4 h0 = *(const float4*)(pr);       // wave-uniform -> broadcast
    const float4 h1 = *(const float4*)(pr + 4);
    const float4 h2 = *(const float4*)(pr + 8);
    const float4 h3 = *(const float4*)(pr + 12);
    const float hk[16] = {
      fmaxf(h0.x,0.f), fmaxf(h0.y,0.f), fmaxf(h0.z,0.f), fmaxf(h0.w,0.f),
      fmaxf(h1.x,0.f), fmaxf(h1.y,0.f), fmaxf(h1.z,0.f), fmaxf(h1.w,0.f),
      fmaxf(h2.x,0.f), fmaxf(h2.y,0.f), fmaxf(h2.z,0.f), fmaxf(h2.w,0.f),
      fmaxf(h3.x,0.f), fmaxf(h3.y,0.f), fmaxf(h3.z,0.f), fmaxf(h3.w,0.f) };
    float a0 = 0.f, a1 = 0.f;
#pragma unroll
    for (int k = 0; k < 16; ++k) {
      a0 = fmaf(hk[k], wx[k], a0);
      a1 = fmaf(hk[k], wy[k], a1);
    }
    atomicAdd(&pout[rr][l],      a0);         // native ds_add_f32 (verified R5)
    atomicAdd(&pout[rr][l + 64], a1);
  }
}

__global__ void __launch_bounds__(NTHR, 4)
cde_main(const float* __restrict__ coeffs, const int* __restrict__ yy,
         const float* __restrict__ times,
         const float* __restrict__ W_init, const float* __restrict__ b_init,
         const float* __restrict__ W_in,  const float* __restrict__ b_in,
         const float* __restrict__ W_h,   const float* __restrict__ b_h,
         const float* __restrict__ W_out, const float* __restrict__ b_out,
         const float* __restrict__ W_read,const float* __restrict__ b_read,
         float* __restrict__ out)
{
  __shared__ float sZs[MROWS][HD];        // 2KB   stage-input z
  __shared__ float pA [MROWS][HHD];       // 4KB   bias-primed partials, layer A
  __shared__ float p1 [MROWS][HHD];       // 4KB   hidden1
  __shared__ float p2 [MROWS][HHD];       // 4KB   hidden2
  __shared__ float pB [MROWS][576];       // 18KB  big layer, addr = col + (col>>3)
  __shared__ float sDx[MROWS][CC];
  __shared__ float sLog[MROWS][OO];

  const int t    = threadIdx.x;
  const int wv   = t >> 6;        // wave id 0..15
  const int l    = t & 63;        // lane
  const int row0 = blockIdx.x * MROWS;
  // P1-P3 mapping: k-slice ks8 = wv&7, row-half rb = 4*(wv>>3)
  // P4  mapping: k-slice ks8 (16 k), col-half = wv>>3 (256 cols, 4/lane)
  const int ks8  = wv & 7;
  const int rb   = 4 * (wv >> 3);
  const int colb = 256 * (wv >> 3) + 4 * l;
  const int stag = wv & 3;

  // tiny persistent scalars only
  const float binx = b_in[l],      biny = b_in[l + 64];
  const float b1x  = b_h[l],       b1y  = b_h[l + 64];
  const float b2x  = b_h[HHD + l], b2y  = b_h[HHD + l + 64];
  const float boutv = (t < HD*CC) ? b_out[t] : 0.0f;

  // ---- z0 ; thread owns (row wv, h=l) for RK state (waves 0..7) ----
  float z0 = 0.f, kacc = 0.f;
  if (wv < MROWS) {
    const float* cf = coeffs + (size_t)(row0 + wv) * (TT*CC);
    float a = b_init[l];
#pragma unroll
    for (int c = 0; c < CC; ++c) a = fmaf(cf[c], W_init[c*HD + l], a);
    z0 = a;
    sZs[wv][l] = a;
    // ---- prime partial buffers with bias ----
    pA[wv][l] = binx;  pA[wv][l + 64] = biny;
    p1[wv][l] = b1x;   p1[wv][l + 64] = b1y;
    p2[wv][l] = b2x;   p2[wv][l + 64] = b2y;
  }
  if (t < HD*CC) {
#pragma unroll
    for (int r = 0; r < MROWS; ++r) pB[r][t + (t >> 3)] = boutv;
  }
  __syncthreads();

#pragma unroll 1
  for (int step = 0; step < TT-1; ++step) {
    const float dti = times[step+1] - times[step];
    if (t < 64) {   // sDx readers (P5) are barrier-separated both directions
      const int r = t >> 3, c = t & 7;
      const float* cf = coeffs + (size_t)(row0 + r)*(TT*CC) + step*CC + c;
      sDx[r][c] = (cf[CC] - cf[0]) / dti;
    }

#pragma unroll 1
    for (int s = 0; s < 4; ++s) {
      // ---- P1: layer A. rows [rb,rb+4), k in [8ks8,8ks8+8). + prime pB ----
      {
        const int kb = 8 * ks8;
        float wx[8], wy[8];
#pragma unroll
        for (int j = 0; j < 8; ++j) {
          const float* wr = W_in + (kb + j) * HHD;
          wx[j] = wr[l];
          wy[j] = wr[l + 64];
        }
#pragma unroll
        for (int i = 0; i < 4; ++i) {
          const int rr = rb + ((i + stag) & 3);
          const float* zr = &sZs[rr][kb];
          const float4 za = *(const float4*)(zr);
          const float4 zb = *(const float4*)(zr + 4);
          const float zk[8] = {za.x, za.y, za.z, za.w, zb.x, zb.y, zb.z, zb.w};
          float a0 = 0.f, a1 = 0.f;
#pragma unroll
          for (int k = 0; k < 8; ++k) {
            a0 = fmaf(zk[k], wx[k], a0);
            a1 = fmaf(zk[k], wy[k], a1);
          }
          atomicAdd(&pA[rr][l],      a0);
          atomicAdd(&pA[rr][l + 64], a1);
        }
        if (t < HD*CC) {
#pragma unroll
          for (int r = 0; r < MROWS; ++r) pB[r][t + (t >> 3)] = boutv;
        }
      }
      __syncthreads();
      // ---- P2: hidden1 (reads pA, relu inline) ----
      hidden16(W_h, pA, p1, l, 16*ks8, rb, stag);
      __syncthreads();
      // ---- P3: hidden2 (reads p1) + rebias pA ----
      hidden16(W_h + HHD*HHD, p1, p2, l, 16*ks8, rb, stag);
      if (wv < MROWS) { pA[wv][l] = binx;  pA[wv][l + 64] = biny; }
      __syncthreads();
      // ---- P4: big layer. k in [16ks8,16ks8+16), cols colb..colb+3.
      //      acc index ii is the ITERATION (compile-time); the staggered row
      //      (ii+ks8)&7 appears only in LDS addresses -> no scratch (rule #20),
      //      zero same-address atomic collisions. + rebias p1 ----
      {
        float acc[MROWS][4];
#pragma unroll
        for (int r = 0; r < MROWS; ++r)
#pragma unroll
          for (int c = 0; c < 4; ++c) acc[r][c] = 0.f;

        const float* wp = W_out + (size_t)(16*ks8) * (HD*CC) + colb;
#pragma unroll
        for (int kc = 0; kc < 4; ++kc) {
          float4 w4[4];                         // 16 regs, chunk-local
#pragma unroll
          for (int j = 0; j < 4; ++j)
            w4[j] = *(const float4*)(wp + (4*kc + j)*(HD*CC));   // 1KB/wave
          const int k0 = 16*ks8 + 4*kc;
#pragma unroll
          for (int ii = 0; ii < MROWS; ++ii) {
            const int r = (ii + ks8) & 7;                        // LDS addr only
            const float4 hv = *(const float4*)&p2[r][k0];        // broadcast
            const float hf[4] = { fmaxf(hv.x,0.f), fmaxf(hv.y,0.f),
                                  fmaxf(hv.z,0.f), fmaxf(hv.w,0.f) };
#pragma unroll
            for (int j = 0; j < 4; ++j) {
              acc[ii][0] = fmaf(hf[j], w4[j].x, acc[ii][0]);
              acc[ii][1] = fmaf(hf[j], w4[j].y, acc[ii][1]);
              acc[ii][2] = fmaf(hf[j], w4[j].z, acc[ii][2]);
              acc[ii][3] = fmaf(hf[j], w4[j].w, acc[ii][3]);
            }
          }
        }
#pragma unroll
        for (int ii = 0; ii < MROWS; ++ii) {
          const int r = (ii + ks8) & 7;         // staggered: no collisions
#pragma unroll
          for (int c = 0; c < 4; ++c) {
            const int col = colb + c;
            atomicAdd(&pB[r][col + (col >> 3)], acc[ii][c]);
          }
        }
        if (wv < MROWS) { p1[wv][l] = b1x;  p1[wv][l + 64] = b1y; }
      }
      __syncthreads();
      // ---- P5: epilogue (tanh, einsum dX, RK) + rebias p2 (waves 0..7) ----
      if (wv < MROWS) {
        const float* pr = &pB[wv][9*l];       // cols 8l..8l+7, stride-9 conflict-free
        const float u0 = pr[0], u1 = pr[1], u2 = pr[2], u3 = pr[3];
        const float u4 = pr[4], u5 = pr[5], u6 = pr[6], u7 = pr[7];
        const float4 d0 = *(const float4*)&sDx[wv][0];   // broadcast
        const float4 d1 = *(const float4*)&sDx[wv][4];
        float g = fast_tanh(u0)*d0.x + fast_tanh(u1)*d0.y
                + fast_tanh(u2)*d0.z + fast_tanh(u3)*d0.w
                + fast_tanh(u4)*d1.x + fast_tanh(u5)*d1.y
                + fast_tanh(u6)*d1.z + fast_tanh(u7)*d1.w;
        if (s == 0)      kacc = g;
        else if (s == 3) kacc += g;
        else             kacc += 2.0f * g;
        float zs;
        if (s == 3) {
          z0 = z0 + dti * (1.0f/6.0f) * kacc;
          zs = z0;
        } else {
          zs = z0 + ((s == 2) ? dti : 0.5f * dti) * g;
        }
        sZs[wv][l] = zs;
        p2[wv][l] = b2x;  p2[wv][l + 64] = b2y;
      }
      __syncthreads();
    } // stages
  }   // steps

  // ---- readout: logits = zT @ W_read + b_read ; loss + accuracy ----
  if (t < MROWS * OO) {
    const int r = t / OO, o = t % OO;
    float a = b_read[o];
#pragma unroll 8
    for (int k = 0; k < HD; ++k) a = fmaf(sZs[r][k], W_read[k*OO + o], a);
    sLog[r][o] = a;
  }
  __syncthreads();
  if (t < 64) {
    float lv = 0.f, cv = 0.f;
    if (t < MROWS) {
      const int r = t;
      float mx = sLog[r][0]; int am = 0;
#pragma unroll
      for (int o = 1; o < OO; ++o) { const float v = sLog[r][o]; if (v > mx) { mx = v; am = o; } }
      float se = 0.f;
#pragma unroll
      for (int o = 0; o < OO; ++o) se += expf(sLog[r][o] - mx);
      const float lse = mx + logf(se);
      const int yr = yy[row0 + r];
      lv = (lse - sLog[r][yr]) * (1.0f / (float)BB);
      cv = (am == yr) ? 1.0f : 0.0f;
    }
    lv += __shfl_xor(lv, 1); lv += __shfl_xor(lv, 2); lv += __shfl_xor(lv, 4);
    cv += __shfl_xor(cv, 1); cv += __shfl_xor(cv, 2); cv += __shfl_xor(cv, 4);
    if (t == 0) { atomicAdd(&out[0], lv); atomicAdd(&out[1], cv); }
  }
}

extern "C" void kernel_launch(void* const* d_in, const int* in_sizes, int n_in,
                              void* d_out, int out_size, void* d_ws, size_t ws_size,
                              hipStream_t stream) {
  const float* coeffs = (const float*)d_in[0];
  const int*   y      = (const int*)  d_in[1];
  const float* times  = (const float*)d_in[2];
  const float* W_init = (const float*)d_in[3];
  const float* b_init = (const float*)d_in[4];
  const float* W_in   = (const float*)d_in[5];
  const float* b_in   = (const float*)d_in[6];
  const float* W_h    = (const float*)d_in[7];
  const float* b_h    = (const float*)d_in[8];
  const float* W_out  = (const float*)d_in[9];
  const float* b_out  = (const float*)d_in[10];
  const float* W_read = (const float*)d_in[11];
  const float* b_read = (const float*)d_in[12];
  float* out = (float*)d_out;

  zero_out_k<<<1, 64, 0, stream>>>(out);   // d_out is poisoned 0xAA before every replay
  cde_main<<<BB/MROWS, NTHR, 0, stream>>>(coeffs, y, times, W_init, b_init,
                                          W_in, b_in, W_h, b_h, W_out, b_out,
                                          W_read, b_read, out);
}

// Round 7
// 19622.208 us; speedup vs baseline: 2.3167x; 2.3167x over previous
//
#include <hip/hip_runtime.h>

// Problem constants (from reference)
#define BB    2048
#define TT    100
#define CC    8
#define HD    64
#define HHD   128
#define OO    10
#define MROWS 8      // batch rows per block; grid = 256 blocks = 1 block/CU
#define NTHR  512    // 8 waves/block = 2 waves/SIMD

// Ledger:
// R1: 2 blocks/CU (MROWS=4): 2x per-CU weight refetch -> -35%. Reverted.
// R3: register-cached weights: FETCH 1.2e7->5e3 KB, dur FLAT -> not BW-bound.
// R4: readlane restructure: scratch spill -> confounded. Reverted.
// R5: asm ds_add_f32: bank-conflict counter identical => atomicAdd already
//     native; asm "memory" fence cost -33%. Reverted.
// R6: 1024-thr blocks: launch_bounds(1024,4) -> 64-VGPR cap -> 27GB scratch
//     spill (WRITE_SIZE), -2.4x. Reverted.
// Cross-round accounting: VALU ~22k cy + LDS-pipe ~18k cy per CU-substage vs
// wall 112-135k cy, even with ZERO in-loop global traffic (R3) => stall is
// per-instruction LATENCY EXPOSURE: ds_read ~120cy / L2 ~200-900cy, consumed
// immediately after issue, lockstep across both waves of a SIMD. R0's VGPR
// pinned at 128 (4-wave default) left no room to batch.
// R7 (this): R0 structure EXACTLY, + launch_bounds(512,2) (256-VGPR cap for
// our 2 waves/SIMD) + every phase rewritten issue-all-loads-then-compute
// (peak live ~150 regs). Tripwires: VGPR_Count must rise >128; WRITE_SIZE
// must stay ~1e3 KB (no spill).

__device__ __forceinline__ float fast_tanh(float x) {
  float e = __expf(2.0f * x);
  return 1.0f - 2.0f / (e + 1.0f);
}

__global__ void zero_out_k(float* o) {
  if (threadIdx.x < 2) o[threadIdx.x] = 0.0f;
}

// Hidden layer slice: rows [rb,rb+4), k in [kb,kb+32), lane cols (l, l+64).
// BATCHED: all 64 weight loads issued up front (one vmcnt wait for the whole
// phase); activations in 2-row groups of 16 ds_read_b128 (one lgkm wait per
// group) instead of read->consume per row.
__device__ __forceinline__ void hidden_layer(const float* __restrict__ Wg,
                                             const float (*pin)[HHD],
                                             float (*pout)[HHD],
                                             int l, int kb, int rb) {
  float wx[32], wy[32];                       // 64 regs, issued back-to-back
#pragma unroll
  for (int j = 0; j < 32; ++j) {
    const float* wr = Wg + (kb + j) * HHD;
    wx[j] = wr[l];                            // 256B coalesced per wave
    wy[j] = wr[l + 64];
  }
#pragma unroll
  for (int pass = 0; pass < 2; ++pass) {
    float4 hv[2][8];                          // 64 regs, issued back-to-back
#pragma unroll
    for (int rr = 0; rr < 2; ++rr)
#pragma unroll
      for (int c = 0; c < 8; ++c)
        hv[rr][c] = *(const float4*)&pin[rb + 2*pass + rr][kb + 4*c];
#pragma unroll
    for (int rr = 0; rr < 2; ++rr) {
      float a0 = 0.f, a1 = 0.f;
#pragma unroll
      for (int c = 0; c < 8; ++c) {
        const float hk[4] = { fmaxf(hv[rr][c].x,0.f), fmaxf(hv[rr][c].y,0.f),
                              fmaxf(hv[rr][c].z,0.f), fmaxf(hv[rr][c].w,0.f) };
#pragma unroll
        for (int k = 0; k < 4; ++k) {
          a0 = fmaf(hk[k], wx[4*c + k], a0);
          a1 = fmaf(hk[k], wy[4*c + k], a1);
        }
      }
      atomicAdd(&pout[rb + 2*pass + rr][l],      a0);  // native ds_add_f32
      atomicAdd(&pout[rb + 2*pass + rr][l + 64], a1);
    }
  }
}

__global__ void __launch_bounds__(NTHR, 2)
cde_main(const float* __restrict__ coeffs, const int* __restrict__ yy,
         const float* __restrict__ times,
         const float* __restrict__ W_init, const float* __restrict__ b_init,
         const float* __restrict__ W_in,  const float* __restrict__ b_in,
         const float* __restrict__ W_h,   const float* __restrict__ b_h,
         const float* __restrict__ W_out, const float* __restrict__ b_out,
         const float* __restrict__ W_read,const float* __restrict__ b_read,
         float* __restrict__ out)
{
  __shared__ float sZs[MROWS][HD];        // 2KB   stage-input z
  __shared__ float pA [MROWS][HHD];       // 4KB   bias-primed partials, layer A
  __shared__ float p1 [MROWS][HHD];       // 4KB   hidden1
  __shared__ float p2 [MROWS][HHD];       // 4KB   hidden2
  __shared__ float pB [MROWS][576];       // 18KB  big layer, addr = col + (col>>3)
  __shared__ float sDx[MROWS][CC];
  __shared__ float sLog[MROWS][OO];

  const int t    = threadIdx.x;
  const int wv   = t >> 6;        // wave id 0..7
  const int l    = t & 63;        // lane
  const int row0 = blockIdx.x * MROWS;
  // P1-P3 mapping: k-slice q = wv&3, row-group rb = 4*(wv>>2)
  const int q    = wv & 3;
  const int rb   = 4 * (wv >> 2);
  // P4 mapping: k-slice q (32k), col-half = wv>>2 (256 cols, 4/lane)
  const int colb = 256 * (wv >> 2) + 4 * l;

  // tiny persistent scalars only
  const float binx = b_in[l],      biny = b_in[l + 64];
  const float b1x  = b_h[l],       b1y  = b_h[l + 64];
  const float b2x  = b_h[HHD + l], b2y  = b_h[HHD + l + 64];
  const float boutv = b_out[t];

  // ---- z0 ; thread owns (row wv, h=l) for RK state ----
  float z0, kacc = 0.f;
  {
    const float* cf = coeffs + (size_t)(row0 + wv) * (TT*CC);
    float a = b_init[l];
#pragma unroll
    for (int c = 0; c < CC; ++c) a = fmaf(cf[c], W_init[c*HD + l], a);
    z0 = a;
    sZs[wv][l] = a;
  }

  // ---- prime partial buffers with bias ----
  pA[wv][l] = binx;  pA[wv][l + 64] = biny;
  p1[wv][l] = b1x;   p1[wv][l + 64] = b1y;
  p2[wv][l] = b2x;   p2[wv][l + 64] = b2y;
#pragma unroll
  for (int r = 0; r < MROWS; ++r) pB[r][t + (t >> 3)] = boutv;
  __syncthreads();

#pragma unroll 1
  for (int step = 0; step < TT-1; ++step) {
    const float dti = times[step+1] - times[step];
    if (t < 64) {   // sDx readers (P5) are barrier-separated both directions
      const int r = t >> 3, c = t & 7;
      const float* cf = coeffs + (size_t)(row0 + r)*(TT*CC) + step*CC + c;
      sDx[r][c] = (cf[CC] - cf[0]) / dti;
    }

#pragma unroll 1
    for (int s = 0; s < 4; ++s) {
      // ---- P1: layer A. rows [rb,rb+4), k in [16q,16q+16). BATCHED.
      //      + prime pB ----
      {
        const int kb = 16 * q;
        float wx[16], wy[16];
#pragma unroll
        for (int j = 0; j < 16; ++j) {
          const float* wr = W_in + (kb + j) * HHD;
          wx[j] = wr[l];
          wy[j] = wr[l + 64];
        }
        float4 zv[4][4];                      // 64 regs, issued back-to-back
#pragma unroll
        for (int rr = 0; rr < 4; ++rr)
#pragma unroll
          for (int c = 0; c < 4; ++c)
            zv[rr][c] = *(const float4*)&sZs[rb + rr][kb + 4*c];
#pragma unroll
        for (int rr = 0; rr < 4; ++rr) {
          float a0 = 0.f, a1 = 0.f;
#pragma unroll
          for (int c = 0; c < 4; ++c) {
            const float zk[4] = {zv[rr][c].x, zv[rr][c].y,
                                 zv[rr][c].z, zv[rr][c].w};
#pragma unroll
            for (int k = 0; k < 4; ++k) {
              a0 = fmaf(zk[k], wx[4*c + k], a0);
              a1 = fmaf(zk[k], wy[4*c + k], a1);
            }
          }
          atomicAdd(&pA[rb + rr][l],      a0);
          atomicAdd(&pA[rb + rr][l + 64], a1);
        }
#pragma unroll
        for (int r = 0; r < MROWS; ++r) pB[r][t + (t >> 3)] = boutv;
      }
      __syncthreads();
      // ---- P2: hidden1 (reads pA, relu inline) ----
      hidden_layer(W_h, pA, p1, l, 32*q, rb);
      __syncthreads();
      // ---- P3: hidden2 (reads p1) + rebias pA ----
      hidden_layer(W_h + HHD*HHD, p1, p2, l, 32*q, rb);
      pA[wv][l] = binx;  pA[wv][l + 64] = biny;
      __syncthreads();
      // ---- P4: big layer. k in [32q,32q+32), cols colb..colb+3.
      //      Weights in 4-chunk halves (16 global loads batched per half),
      //      8 ds_read_b128 batched per chunk. + rebias p1 ----
      {
        float acc[MROWS][4];
#pragma unroll
        for (int r = 0; r < MROWS; ++r)
#pragma unroll
          for (int c = 0; c < 4; ++c) acc[r][c] = 0.f;

        const float* wp = W_out + (size_t)(32*q) * (HD*CC) + colb;
#pragma unroll
        for (int half = 0; half < 2; ++half) {
          float4 w4[4][4];                    // 64 regs, issued back-to-back
#pragma unroll
          for (int kc = 0; kc < 4; ++kc)
#pragma unroll
            for (int j = 0; j < 4; ++j)
              w4[kc][j] = *(const float4*)(wp + (16*half + 4*kc + j)*(HD*CC));
#pragma unroll
          for (int kc = 0; kc < 4; ++kc) {
            const int k0 = 32*q + 16*half + 4*kc;
            float4 pv[8];                     // 32 regs, issued back-to-back
#pragma unroll
            for (int r = 0; r < MROWS; ++r)
              pv[r] = *(const float4*)&p2[r][k0];
#pragma unroll
            for (int r = 0; r < MROWS; ++r) {
              const float hf[4] = { fmaxf(pv[r].x,0.f), fmaxf(pv[r].y,0.f),
                                    fmaxf(pv[r].z,0.f), fmaxf(pv[r].w,0.f) };
#pragma unroll
              for (int j = 0; j < 4; ++j) {
                acc[r][0] = fmaf(hf[j], w4[kc][j].x, acc[r][0]);
                acc[r][1] = fmaf(hf[j], w4[kc][j].y, acc[r][1]);
                acc[r][2] = fmaf(hf[j], w4[kc][j].z, acc[r][2]);
                acc[r][3] = fmaf(hf[j], w4[kc][j].w, acc[r][3]);
              }
            }
          }
        }
#pragma unroll
        for (int r = 0; r < MROWS; ++r)
#pragma unroll
          for (int c = 0; c < 4; ++c) {
            const int col = colb + c;
            atomicAdd(&pB[r][col + (col >> 3)], acc[r][c]);
          }
        p1[wv][l] = b1x;  p1[wv][l + 64] = b1y;
      }
      __syncthreads();
      // ---- P5: epilogue (tanh, einsum dX, RK) + rebias p2 ----
      {
        const float* pr = &pB[wv][9*l];       // cols 8l..8l+7, stride-9 conflict-free
        const float u0 = pr[0], u1 = pr[1], u2 = pr[2], u3 = pr[3];
        const float u4 = pr[4], u5 = pr[5], u6 = pr[6], u7 = pr[7];
        const float4 d0 = *(const float4*)&sDx[wv][0];   // broadcast
        const float4 d1 = *(const float4*)&sDx[wv][4];
        float g = fast_tanh(u0)*d0.x + fast_tanh(u1)*d0.y
                + fast_tanh(u2)*d0.z + fast_tanh(u3)*d0.w
                + fast_tanh(u4)*d1.x + fast_tanh(u5)*d1.y
                + fast_tanh(u6)*d1.z + fast_tanh(u7)*d1.w;
        if (s == 0)      kacc = g;
        else if (s == 3) kacc += g;
        else             kacc += 2.0f * g;
        float zs;
        if (s == 3) {
          z0 = z0 + dti * (1.0f/6.0f) * kacc;
          zs = z0;
        } else {
          zs = z0 + ((s == 2) ? dti : 0.5f * dti) * g;
        }
        sZs[wv][l] = zs;
        p2[wv][l] = b2x;  p2[wv][l + 64] = b2y;
      }
      __syncthreads();
    } // stages
  }   // steps

  // ---- readout: logits = zT @ W_read + b_read ; loss + accuracy ----
  if (t < MROWS * OO) {
    const int r = t / OO, o = t % OO;
    float a = b_read[o];
#pragma unroll 8
    for (int k = 0; k < HD; ++k) a = fmaf(sZs[r][k], W_read[k*OO + o], a);
    sLog[r][o] = a;
  }
  __syncthreads();
  if (t < 64) {
    float lv = 0.f, cv = 0.f;
    if (t < MROWS) {
      const int r = t;
      float mx = sLog[r][0]; int am = 0;
#pragma unroll
      for (int o = 1; o < OO; ++o) { const float v = sLog[r][o]; if (v > mx) { mx = v; am = o; } }
      float se = 0.f;
#pragma unroll
      for (int o = 0; o < OO; ++o) se += expf(sLog[r][o] - mx);
      const float lse = mx + logf(se);
      const int yr = yy[row0 + r];
      lv = (lse - sLog[r][yr]) * (1.0f / (float)BB);
      cv = (am == yr) ? 1.0f : 0.0f;
    }
    lv += __shfl_xor(lv, 1); lv += __shfl_xor(lv, 2); lv += __shfl_xor(lv, 4);
    cv += __shfl_xor(cv, 1); cv += __shfl_xor(cv, 2); cv += __shfl_xor(cv, 4);
    if (t == 0) { atomicAdd(&out[0], lv); atomicAdd(&out[1], cv); }
  }
}

extern "C" void kernel_launch(void* const* d_in, const int* in_sizes, int n_in,
                              void* d_out, int out_size, void* d_ws, size_t ws_size,
                              hipStream_t stream) {
  const float* coeffs = (const float*)d_in[0];
  const int*   y      = (const int*)  d_in[1];
  const float* times  = (const float*)d_in[2];
  const float* W_init = (const float*)d_in[3];
  const float* b_init = (const float*)d_in[4];
  const float* W_in   = (const float*)d_in[5];
  const float* b_in   = (const float*)d_in[6];
  const float* W_h    = (const float*)d_in[7];
  const float* b_h    = (const float*)d_in[8];
  const float* W_out  = (const float*)d_in[9];
  const float* b_out  = (const float*)d_in[10];
  const float* W_read = (const float*)d_in[11];
  const float* b_read = (const float*)d_in[12];
  float* out = (float*)d_out;

  zero_out_k<<<1, 64, 0, stream>>>(out);   // d_out is poisoned 0xAA before every replay
  cde_main<<<BB/MROWS, NTHR, 0, stream>>>(coeffs, y, times, W_init, b_init,
                                          W_in, b_in, W_h, b_h, W_out, b_out,
                                          W_read, b_read, out);
}

// Round 8
// 19609.962 us; speedup vs baseline: 2.3181x; 1.0006x over previous
//
#include <hip/hip_runtime.h>

// Problem constants (from reference)
#define BB    2048
#define TT    100
#define CC    8
#define HD    64
#define HHD   128
#define OO    10
#define MROWS 8      // batch rows per block; grid = 256 blocks = 1 block/CU
#define NTHR  512    // 8 waves/block = 2 waves/SIMD

// Ledger:
// R1: 2 blocks/CU (MROWS=4): -35%. Reverted.
// R3: register-cached weights: FETCH 1.2e7->5e3 KB, dur FLAT -> not BW-bound.
// R4: readlane restructure: scratch spill -> confounded. Reverted.
// R5: asm ds_add_f32: identical bank-conflict counter => atomicAdd already
//     native ds_add_f32; asm "memory" fence cost -33%. Reverted.
// R6: 1024-thr: (1024,4) -> 64-VGPR cap -> 27GB spill, -2.4x. Reverted.
// R7: batched-issue phases + (512,2): VGPR PINNED AT 128, WRITE_SIZE 555MB
//     (spill) -> experiment didn't take, dur 19.6ms.
// EMPIRICAL launch_bounds decode (contradicts guide): 2nd arg acts as MIN
// BLOCKS PER CU (CUDA semantics): (512,4)->64 regs, (512,2)->128, need
// (512,1) for the 256-reg cap. Grid is 1 block/CU anyway -> no occupancy loss.
// R8 (this): R7 byte-identical EXCEPT __launch_bounds__(512,1).
// Theory: per-phase wall ~22k cy for ~300 instrs = ~73cy/instr full latency
// exposure; 128-reg budget forces load->wait->consume serialization. 256-reg
// budget lets the batched-issue structure pay ~2 vmcnt waits per phase.
// Tripwires: VGPR_Count must rise >128; WRITE_SIZE must drop to ~1e3 KB.

__device__ __forceinline__ float fast_tanh(float x) {
  float e = __expf(2.0f * x);
  return 1.0f - 2.0f / (e + 1.0f);
}

__global__ void zero_out_k(float* o) {
  if (threadIdx.x < 2) o[threadIdx.x] = 0.0f;
}

// Hidden layer slice: rows [rb,rb+4), k in [kb,kb+32), lane cols (l, l+64).
// BATCHED: all 64 weight loads issued up front (one vmcnt wait for the whole
// phase); activations in 2-row groups of 16 ds_read_b128 (one lgkm wait per
// group) instead of read->consume per row.
__device__ __forceinline__ void hidden_layer(const float* __restrict__ Wg,
                                             const float (*pin)[HHD],
                                             float (*pout)[HHD],
                                             int l, int kb, int rb) {
  float wx[32], wy[32];                       // 64 regs, issued back-to-back
#pragma unroll
  for (int j = 0; j < 32; ++j) {
    const float* wr = Wg + (kb + j) * HHD;
    wx[j] = wr[l];                            // 256B coalesced per wave
    wy[j] = wr[l + 64];
  }
#pragma unroll
  for (int pass = 0; pass < 2; ++pass) {
    float4 hv[2][8];                          // 64 regs, issued back-to-back
#pragma unroll
    for (int rr = 0; rr < 2; ++rr)
#pragma unroll
      for (int c = 0; c < 8; ++c)
        hv[rr][c] = *(const float4*)&pin[rb + 2*pass + rr][kb + 4*c];
#pragma unroll
    for (int rr = 0; rr < 2; ++rr) {
      float a0 = 0.f, a1 = 0.f;
#pragma unroll
      for (int c = 0; c < 8; ++c) {
        const float hk[4] = { fmaxf(hv[rr][c].x,0.f), fmaxf(hv[rr][c].y,0.f),
                              fmaxf(hv[rr][c].z,0.f), fmaxf(hv[rr][c].w,0.f) };
#pragma unroll
        for (int k = 0; k < 4; ++k) {
          a0 = fmaf(hk[k], wx[4*c + k], a0);
          a1 = fmaf(hk[k], wy[4*c + k], a1);
        }
      }
      atomicAdd(&pout[rb + 2*pass + rr][l],      a0);  // native ds_add_f32
      atomicAdd(&pout[rb + 2*pass + rr][l + 64], a1);
    }
  }
}

__global__ void __launch_bounds__(NTHR, 1)
cde_main(const float* __restrict__ coeffs, const int* __restrict__ yy,
         const float* __restrict__ times,
         const float* __restrict__ W_init, const float* __restrict__ b_init,
         const float* __restrict__ W_in,  const float* __restrict__ b_in,
         const float* __restrict__ W_h,   const float* __restrict__ b_h,
         const float* __restrict__ W_out, const float* __restrict__ b_out,
         const float* __restrict__ W_read,const float* __restrict__ b_read,
         float* __restrict__ out)
{
  __shared__ float sZs[MROWS][HD];        // 2KB   stage-input z
  __shared__ float pA [MROWS][HHD];       // 4KB   bias-primed partials, layer A
  __shared__ float p1 [MROWS][HHD];       // 4KB   hidden1
  __shared__ float p2 [MROWS][HHD];       // 4KB   hidden2
  __shared__ float pB [MROWS][576];       // 18KB  big layer, addr = col + (col>>3)
  __shared__ float sDx[MROWS][CC];
  __shared__ float sLog[MROWS][OO];

  const int t    = threadIdx.x;
  const int wv   = t >> 6;        // wave id 0..7
  const int l    = t & 63;        // lane
  const int row0 = blockIdx.x * MROWS;
  // P1-P3 mapping: k-slice q = wv&3, row-group rb = 4*(wv>>2)
  const int q    = wv & 3;
  const int rb   = 4 * (wv >> 2);
  // P4 mapping: k-slice q (32k), col-half = wv>>2 (256 cols, 4/lane)
  const int colb = 256 * (wv >> 2) + 4 * l;

  // tiny persistent scalars only
  const float binx = b_in[l],      biny = b_in[l + 64];
  const float b1x  = b_h[l],       b1y  = b_h[l + 64];
  const float b2x  = b_h[HHD + l], b2y  = b_h[HHD + l + 64];
  const float boutv = b_out[t];

  // ---- z0 ; thread owns (row wv, h=l) for RK state ----
  float z0, kacc = 0.f;
  {
    const float* cf = coeffs + (size_t)(row0 + wv) * (TT*CC);
    float a = b_init[l];
#pragma unroll
    for (int c = 0; c < CC; ++c) a = fmaf(cf[c], W_init[c*HD + l], a);
    z0 = a;
    sZs[wv][l] = a;
  }

  // ---- prime partial buffers with bias ----
  pA[wv][l] = binx;  pA[wv][l + 64] = biny;
  p1[wv][l] = b1x;   p1[wv][l + 64] = b1y;
  p2[wv][l] = b2x;   p2[wv][l + 64] = b2y;
#pragma unroll
  for (int r = 0; r < MROWS; ++r) pB[r][t + (t >> 3)] = boutv;
  __syncthreads();

#pragma unroll 1
  for (int step = 0; step < TT-1; ++step) {
    const float dti = times[step+1] - times[step];
    if (t < 64) {   // sDx readers (P5) are barrier-separated both directions
      const int r = t >> 3, c = t & 7;
      const float* cf = coeffs + (size_t)(row0 + r)*(TT*CC) + step*CC + c;
      sDx[r][c] = (cf[CC] - cf[0]) / dti;
    }

#pragma unroll 1
    for (int s = 0; s < 4; ++s) {
      // ---- P1: layer A. rows [rb,rb+4), k in [16q,16q+16). BATCHED.
      //      + prime pB ----
      {
        const int kb = 16 * q;
        float wx[16], wy[16];
#pragma unroll
        for (int j = 0; j < 16; ++j) {
          const float* wr = W_in + (kb + j) * HHD;
          wx[j] = wr[l];
          wy[j] = wr[l + 64];
        }
        float4 zv[4][4];                      // 64 regs, issued back-to-back
#pragma unroll
        for (int rr = 0; rr < 4; ++rr)
#pragma unroll
          for (int c = 0; c < 4; ++c)
            zv[rr][c] = *(const float4*)&sZs[rb + rr][kb + 4*c];
#pragma unroll
        for (int rr = 0; rr < 4; ++rr) {
          float a0 = 0.f, a1 = 0.f;
#pragma unroll
          for (int c = 0; c < 4; ++c) {
            const float zk[4] = {zv[rr][c].x, zv[rr][c].y,
                                 zv[rr][c].z, zv[rr][c].w};
#pragma unroll
            for (int k = 0; k < 4; ++k) {
              a0 = fmaf(zk[k], wx[4*c + k], a0);
              a1 = fmaf(zk[k], wy[4*c + k], a1);
            }
          }
          atomicAdd(&pA[rb + rr][l],      a0);
          atomicAdd(&pA[rb + rr][l + 64], a1);
        }
#pragma unroll
        for (int r = 0; r < MROWS; ++r) pB[r][t + (t >> 3)] = boutv;
      }
      __syncthreads();
      // ---- P2: hidden1 (reads pA, relu inline) ----
      hidden_layer(W_h, pA, p1, l, 32*q, rb);
      __syncthreads();
      // ---- P3: hidden2 (reads p1) + rebias pA ----
      hidden_layer(W_h + HHD*HHD, p1, p2, l, 32*q, rb);
      pA[wv][l] = binx;  pA[wv][l + 64] = biny;
      __syncthreads();
      // ---- P4: big layer. k in [32q,32q+32), cols colb..colb+3.
      //      Weights in 4-chunk halves (16 global loads batched per half),
      //      8 ds_read_b128 batched per chunk. + rebias p1 ----
      {
        float acc[MROWS][4];
#pragma unroll
        for (int r = 0; r < MROWS; ++r)
#pragma unroll
          for (int c = 0; c < 4; ++c) acc[r][c] = 0.f;

        const float* wp = W_out + (size_t)(32*q) * (HD*CC) + colb;
#pragma unroll
        for (int half = 0; half < 2; ++half) {
          float4 w4[4][4];                    // 64 regs, issued back-to-back
#pragma unroll
          for (int kc = 0; kc < 4; ++kc)
#pragma unroll
            for (int j = 0; j < 4; ++j)
              w4[kc][j] = *(const float4*)(wp + (16*half + 4*kc + j)*(HD*CC));
#pragma unroll
          for (int kc = 0; kc < 4; ++kc) {
            const int k0 = 32*q + 16*half + 4*kc;
            float4 pv[8];                     // 32 regs, issued back-to-back
#pragma unroll
            for (int r = 0; r < MROWS; ++r)
              pv[r] = *(const float4*)&p2[r][k0];
#pragma unroll
            for (int r = 0; r < MROWS; ++r) {
              const float hf[4] = { fmaxf(pv[r].x,0.f), fmaxf(pv[r].y,0.f),
                                    fmaxf(pv[r].z,0.f), fmaxf(pv[r].w,0.f) };
#pragma unroll
              for (int j = 0; j < 4; ++j) {
                acc[r][0] = fmaf(hf[j], w4[kc][j].x, acc[r][0]);
                acc[r][1] = fmaf(hf[j], w4[kc][j].y, acc[r][1]);
                acc[r][2] = fmaf(hf[j], w4[kc][j].z, acc[r][2]);
                acc[r][3] = fmaf(hf[j], w4[kc][j].w, acc[r][3]);
              }
            }
          }
        }
#pragma unroll
        for (int r = 0; r < MROWS; ++r)
#pragma unroll
          for (int c = 0; c < 4; ++c) {
            const int col = colb + c;
            atomicAdd(&pB[r][col + (col >> 3)], acc[r][c]);
          }
        p1[wv][l] = b1x;  p1[wv][l + 64] = b1y;
      }
      __syncthreads();
      // ---- P5: epilogue (tanh, einsum dX, RK) + rebias p2 ----
      {
        const float* pr = &pB[wv][9*l];       // cols 8l..8l+7, stride-9 conflict-free
        const float u0 = pr[0], u1 = pr[1], u2 = pr[2], u3 = pr[3];
        const float u4 = pr[4], u5 = pr[5], u6 = pr[6], u7 = pr[7];
        const float4 d0 = *(const float4*)&sDx[wv][0];   // broadcast
        const float4 d1 = *(const float4*)&sDx[wv][4];
        float g = fast_tanh(u0)*d0.x + fast_tanh(u1)*d0.y
                + fast_tanh(u2)*d0.z + fast_tanh(u3)*d0.w
                + fast_tanh(u4)*d1.x + fast_tanh(u5)*d1.y
                + fast_tanh(u6)*d1.z + fast_tanh(u7)*d1.w;
        if (s == 0)      kacc = g;
        else if (s == 3) kacc += g;
        else             kacc += 2.0f * g;
        float zs;
        if (s == 3) {
          z0 = z0 + dti * (1.0f/6.0f) * kacc;
          zs = z0;
        } else {
          zs = z0 + ((s == 2) ? dti : 0.5f * dti) * g;
        }
        sZs[wv][l] = zs;
        p2[wv][l] = b2x;  p2[wv][l + 64] = b2y;
      }
      __syncthreads();
    } // stages
  }   // steps

  // ---- readout: logits = zT @ W_read + b_read ; loss + accuracy ----
  if (t < MROWS * OO) {
    const int r = t / OO, o = t % OO;
    float a = b_read[o];
#pragma unroll 8
    for (int k = 0; k < HD; ++k) a = fmaf(sZs[r][k], W_read[k*OO + o], a);
    sLog[r][o] = a;
  }
  __syncthreads();
  if (t < 64) {
    float lv = 0.f, cv = 0.f;
    if (t < MROWS) {
      const int r = t;
      float mx = sLog[r][0]; int am = 0;
#pragma unroll
      for (int o = 1; o < OO; ++o) { const float v = sLog[r][o]; if (v > mx) { mx = v; am = o; } }
      float se = 0.f;
#pragma unroll
      for (int o = 0; o < OO; ++o) se += expf(sLog[r][o] - mx);
      const float lse = mx + logf(se);
      const int yr = yy[row0 + r];
      lv = (lse - sLog[r][yr]) * (1.0f / (float)BB);
      cv = (am == yr) ? 1.0f : 0.0f;
    }
    lv += __shfl_xor(lv, 1); lv += __shfl_xor(lv, 2); lv += __shfl_xor(lv, 4);
    cv += __shfl_xor(cv, 1); cv += __shfl_xor(cv, 2); cv += __shfl_xor(cv, 4);
    if (t == 0) { atomicAdd(&out[0], lv); atomicAdd(&out[1], cv); }
  }
}

extern "C" void kernel_launch(void* const* d_in, const int* in_sizes, int n_in,
                              void* d_out, int out_size, void* d_ws, size_t ws_size,
                              hipStream_t stream) {
  const float* coeffs = (const float*)d_in[0];
  const int*   y      = (const int*)  d_in[1];
  const float* times  = (const float*)d_in[2];
  const float* W_init = (const float*)d_in[3];
  const float* b_init = (const float*)d_in[4];
  const float* W_in   = (const float*)d_in[5];
  const float* b_in   = (const float*)d_in[6];
  const float* W_h    = (const float*)d_in[7];
  const float* b_h    = (const float*)d_in[8];
  const float* W_out  = (const float*)d_in[9];
  const float* b_out  = (const float*)d_in[10];
  const float* W_read = (const float*)d_in[11];
  const float* b_read = (const float*)d_in[12];
  float* out = (float*)d_out;

  zero_out_k<<<1, 64, 0, stream>>>(out);   // d_out is poisoned 0xAA before every replay
  cde_main<<<BB/MROWS, NTHR, 0, stream>>>(coeffs, y, times, W_init, b_init,
                                          W_in, b_in, W_h, b_h, W_out, b_out,
                                          W_read, b_read, out);
}